// Round 8
// baseline (93.029 us; speedup 1.0000x reference)
//
#include <hip/hip_runtime.h>

// input_: (B=64, 2*N=16384, 2, 2, 16) f32 ; diag1/2: (N=8192, 2, 2, 8) f32
// out: (B, N, 2, 2, 23) f32
//   out[b,n,i,j,:] = sum_k conv(x1[b,n,i,k,:], d1[n,k,j,:]) + (x2, d2)
//
// Round 8: decisive occupancy experiment. Thread = (unit, i, j, w-half) so
// acc shrinks 23 -> 12; live set ~50 regs -> target VGPR <= 64 (m69 cliff:
// 8 waves/SIMD) with NO launch_bounds hint (rounds 3/5: hints force spills).
// TILE=32, LDS 8 KB (never binding). x2 prefetched to regs BEFORE compute
// half 1 (round 7 serialized this load behind a barrier). wh = tid bit 7 ->
// wave-uniform, no divergence duplication. If dur stays ~88 us at high
// occupancy, 5.1 TB/s is the real mixed-R/W ceiling (roofline).
#define BB 64
#define NN 8192
#define TILE 32
#define DOUT 23

__device__ __forceinline__ int swz(int G) { return G ^ ((G >> 3) & 7); }

// low half: w in [0,12). acc[w] ; uses x chunks q=0..2 (u=0..11)
__device__ __forceinline__ void compute_low(const float4* __restrict__ sbuf,
                                            const float4* __restrict__ dp,
                                            int unit, int i, float* __restrict__ acc) {
#pragma unroll
    for (int k = 0; k < 2; ++k) {
        float4 dq0 = dp[k * 4 + 0], dq1 = dp[k * 4 + 1];
        const float dv[8] = {dq0.x, dq0.y, dq0.z, dq0.w,
                             dq1.x, dq1.y, dq1.z, dq1.w};
#pragma unroll
        for (int q = 0; q < 3; ++q) {
            float4 xq = sbuf[swz(unit * 16 + i * 8 + k * 4 + q)];
            const float xe[4] = {xq.x, xq.y, xq.z, xq.w};
#pragma unroll
            for (int e = 0; e < 4; ++e) {
                const int u = q * 4 + e;
#pragma unroll
                for (int v = 0; v < 8; ++v) {
                    if (u + v < 12) acc[u + v] += xe[e] * dv[v];
                }
            }
        }
    }
}

// high half: w in [12,23). acc[w-12] ; uses x chunks q=1..3 (u=4..15)
__device__ __forceinline__ void compute_high(const float4* __restrict__ sbuf,
                                             const float4* __restrict__ dp,
                                             int unit, int i, float* __restrict__ acc) {
#pragma unroll
    for (int k = 0; k < 2; ++k) {
        float4 dq0 = dp[k * 4 + 0], dq1 = dp[k * 4 + 1];
        const float dv[8] = {dq0.x, dq0.y, dq0.z, dq0.w,
                             dq1.x, dq1.y, dq1.z, dq1.w};
#pragma unroll
        for (int q = 1; q < 4; ++q) {
            float4 xq = sbuf[swz(unit * 16 + i * 8 + k * 4 + q)];
            const float xe[4] = {xq.x, xq.y, xq.z, xq.w};
#pragma unroll
            for (int e = 0; e < 4; ++e) {
                const int u = q * 4 + e;
#pragma unroll
                for (int v = 0; v < 8; ++v) {
                    if (u + v >= 12) acc[u + v - 12] += xe[e] * dv[v];
                }
            }
        }
    }
}

__global__ __launch_bounds__(256) void hstackdiag_kernel(
    const float* __restrict__ input,
    const float* __restrict__ diag1,
    const float* __restrict__ diag2,
    float* __restrict__ out) {
    __shared__ float4 sbuf[512];  // 8 KB, reused: x1 -> x2 -> output tile

    const int t = threadIdx.x;
    const int bx = blockIdx.x;
    const int b = bx >> 8;               // 256 ntiles per b
    const int n0 = (bx & 255) * TILE;

    // x tile (one half): 32 units x 64 floats = 512 contiguous float4
    const float4* g1 = (const float4*)input + ((size_t)b * (2 * NN) + n0) * 16;
    const float4* g2 = g1 + (size_t)NN * 16;

    const int j = t & 1;
    const int i = (t >> 1) & 1;
    const int unit = (t >> 2) & 31;
    const int wh = t >> 7;               // wave-uniform: waves 0,1 vs 2,3
    const int n = n0 + unit;
    const float4* dp1 = (const float4*)diag1 + (size_t)n * 8 + j * 2;
    const float4* dp2 = (const float4*)diag2 + (size_t)n * 8 + j * 2;

    // Stage x1; PREFETCH x2 into regs now (hide HBM latency under compute 1).
    float4 s0 = g1[t], s1 = g1[256 + t];
    float4 p0 = g2[t], p1 = g2[256 + t];
    sbuf[swz(t)] = s0;
    sbuf[swz(256 + t)] = s1;
    __syncthreads();

    float acc[12];
#pragma unroll
    for (int u = 0; u < 12; ++u) acc[u] = 0.0f;

    if (wh == 0) compute_low(sbuf, dp1, unit, i, acc);
    else         compute_high(sbuf, dp1, unit, i, acc);
    __syncthreads();                     // all waves done reading x1
    sbuf[swz(t)] = p0;
    sbuf[swz(256 + t)] = p1;
    __syncthreads();
    if (wh == 0) compute_low(sbuf, dp2, unit, i, acc);
    else         compute_high(sbuf, dp2, unit, i, acc);
    __syncthreads();                     // done reading x2; reuse sbuf as sout

    // Output: 32 units * 92 floats = 2944 floats, staged 16 units at a time
    // (1472 floats <= 2048-float sbuf), then fully-coalesced stores.
    float* sout = (float*)sbuf;
    const int c = i * 2 + j;
    float* gout = out + ((size_t)b * NN + n0) * (4 * DOUT);

#pragma unroll
    for (int p = 0; p < 2; ++p) {
        if ((unit >> 4) == p) {
            const int base = (unit & 15) * 92 + c * DOUT;
            if (wh == 0) {
#pragma unroll
                for (int q = 0; q < 12; ++q) sout[base + q] = acc[q];
            } else {
#pragma unroll
                for (int q = 0; q < 11; ++q) sout[base + 12 + q] = acc[q];
            }
        }
        __syncthreads();
        // 16 units * 92 = 1472 floats = 5*256 + 192
#pragma unroll
        for (int rr = 0; rr < 5; ++rr)
            gout[p * 1472 + rr * 256 + t] = sout[rr * 256 + t];
        if (t < 192) gout[p * 1472 + 1280 + t] = sout[1280 + t];
        if (p == 0) __syncthreads();     // copies done before pass-1 overwrites
    }
}

extern "C" void kernel_launch(void* const* d_in, const int* in_sizes, int n_in,
                              void* d_out, int out_size, void* d_ws, size_t ws_size,
                              hipStream_t stream) {
    const float* input = (const float*)d_in[0];
    const float* diag1 = (const float*)d_in[1];
    const float* diag2 = (const float*)d_in[2];
    float* out = (float*)d_out;

    const int grid = BB * (NN / TILE);   // 64 * 256 = 16384 blocks
    hstackdiag_kernel<<<grid, 256, 0, stream>>>(input, diag1, diag2, out);
}